// Round 1
// baseline (3874.445 us; speedup 1.0000x reference)
//
#include <hip/hip_runtime.h>
#include <hip/hip_cooperative_groups.h>
#include <cstdint>
#include <cstddef>

namespace cg = cooperative_groups;

#define HN_ 2304
#define G4_ 9216

typedef __attribute__((ext_vector_type(8))) short v8s;
typedef __attribute__((ext_vector_type(4))) float v4f;

__device__ __forceinline__ unsigned short f2bf(float x) {
  union { float f; unsigned int i; } v; v.f = x;
  unsigned int r = (v.i + 0x7fffu + ((v.i >> 16) & 1u)) >> 16;
  return (unsigned short)r;
}

// ---------------- adp = softmax(relu(nv1@nv2), axis=1) ----------------
__global__ __launch_bounds__(256) void adp_kernel(const float* __restrict__ nv1,
                                                  const float* __restrict__ nv2,
                                                  float* __restrict__ adp) {
  int i = blockIdx.x;
  int j = threadIdx.x;
  __shared__ float sm[256];
  float r = 0.f, v = -1e30f;
  if (j < 144) {
    for (int k = 0; k < 10; ++k) r += nv1[i * 10 + k] * nv2[k * 144 + j];
    r = fmaxf(r, 0.f);
    v = r;
  }
  sm[j] = v; __syncthreads();
  for (int s = 128; s > 0; s >>= 1) { if (j < s) sm[j] = fmaxf(sm[j], sm[j + s]); __syncthreads(); }
  float mx = sm[0]; __syncthreads();
  float e = (j < 144) ? expf(r - mx) : 0.f;
  sm[j] = e; __syncthreads();
  for (int s = 128; s > 0; s >>= 1) { if (j < s) sm[j] += sm[j + s]; __syncthreads(); }
  float sum = sm[0];
  if (j < 144) adp[i * 144 + j] = e / sum;
}

// ---------------- layer-0 effective input weights, written as packed bf16 frags ----------------
__global__ __launch_bounds__(256)
void eff_weights(const float* __restrict__ WihF, const float* __restrict__ WihB,
                 const float* __restrict__ bihF, const float* __restrict__ bhhF,
                 const float* __restrict__ bihB, const float* __restrict__ bhhB,
                 const float* __restrict__ ws, const float* __restrict__ bs,
                 const float* __restrict__ wc, const float* __restrict__ bc,
                 unsigned short* __restrict__ Wpk, float* __restrict__ beff) {
  const int r = blockIdx.x, dir = blockIdx.y;
  const float* W = dir ? WihB : WihF;
  __shared__ float red[256];
  const int n = threadIdx.x;
  float spb = 0.f;
  if (n < 144) {
    float sws = 0.f, swc = 0.f;
    #pragma unroll
    for (int c = 0; c < 16; ++c) {
      float w = W[(size_t)r * HN_ + c * 144 + n];
      sws += w * ws[c];
      swc += w * wc[c];
      spb += w * (bs[c] + bc[c]);
    }
    const int rm = r % 2304;
    const int g = r / 2304;
    const int nt = rm >> 2, col = (rm & 3) * 4 + g;
    unsigned short* outp = Wpk + (size_t)dir * 2654208;
    int k = n;
    outp[((size_t)(nt * 9 + (k >> 5)) * 64 + ((k >> 3) & 3) * 16 + col) * 8 + (k & 7)] = f2bf(sws);
    k = 144 + n;
    outp[((size_t)(nt * 9 + (k >> 5)) * 64 + ((k >> 3) & 3) * 16 + col) * 8 + (k & 7)] = f2bf(swc);
  }
  red[n] = spb; __syncthreads();
  for (int s = 128; s > 0; s >>= 1) { if (n < s) red[n] += red[n + s]; __syncthreads(); }
  if (n == 0) {
    const float* bih = dir ? bihB : bihF;
    const float* bhh = dir ? bhhB : bhhF;
    beff[dir * G4_ + r] = red[0] + bih[r] + bhh[r];
  }
}

// ---------------- build A fragments for layer-0 input GEMM (bf16) ----------------
__global__ void build_acat_frag(const float* __restrict__ inF, const float* __restrict__ mF,
                                const float* __restrict__ inB, const float* __restrict__ mB,
                                unsigned short* __restrict__ out) {
  int idx = blockIdx.x * 256 + threadIdx.x;   // 18432 frags total
  int lane = idx & 63;
  int ks = (idx >> 6) % 9;
  int mt = (idx / (64 * 9)) % 16;
  int dir = idx / (64 * 9 * 16);
  int m = mt * 16 + (lane & 15);
  int k = ks * 32 + (lane >> 4) * 8;
  int t = m >> 3, b = m & 7;
  const float* src; int kk = k;
  if (k < 144) src = dir ? inB : inF;
  else { src = dir ? mB : mF; kk = k - 144; }
  const float* p = src + ((size_t)b * 32 + t) * 144 + kk;
  v8s o;
  #pragma unroll
  for (int e = 0; e < 8; ++e) o[e] = (short)f2bf(p[e]);
  ((v8s*)out)[idx] = o;
}

// ---------------- pack a [9216 x 2304] weight matrix into gate-interleaved bf16 frags ----------------
__global__ void pack_whh(const float* __restrict__ W, unsigned short* __restrict__ out) {
  int idx = blockIdx.x * 256 + threadIdx.x;   // 576*72*64 = 2,654,208
  int lane = idx & 63;
  int ks = (idx >> 6) % 72;
  int nt = idx / (64 * 72);
  int col = lane & 15, q = lane >> 4;
  int r = (col & 3) * 2304 + nt * 4 + (col >> 2);
  int k = ks * 32 + q * 8;
  const float* src = W + (size_t)r * 2304 + k;
  float4 v0 = *(const float4*)src;
  float4 v1 = *(const float4*)(src + 4);
  v8s o;
  o[0] = (short)f2bf(v0.x); o[1] = (short)f2bf(v0.y);
  o[2] = (short)f2bf(v0.z); o[3] = (short)f2bf(v0.w);
  o[4] = (short)f2bf(v1.x); o[5] = (short)f2bf(v1.y);
  o[6] = (short)f2bf(v1.z); o[7] = (short)f2bf(v1.w);
  ((v8s*)out)[idx] = o;
}

// ---------------- MFMA GEMM over fragment-packed operands; writes Gx[t][nt][col][b] ----------------
__global__ __launch_bounds__(64)
void gemm_frag(const unsigned short* __restrict__ Apk, const unsigned short* __restrict__ Wpk,
               const float* __restrict__ b1, const float* __restrict__ b2,
               float* __restrict__ Gx, int nks) {
  const int lane = threadIdx.x;
  const int nt = blockIdx.x;
  const int mtb = blockIdx.y * 4;
  v4f acc[4] = {};
  const v8s* Bp = (const v8s*)Wpk + (size_t)nt * nks * 64;
  const v8s* Ap = (const v8s*)Apk;
  for (int ks = 0; ks < nks; ++ks) {
    v8s bf = Bp[ks * 64 + lane];
    #pragma unroll
    for (int mi = 0; mi < 4; ++mi) {
      v8s af = Ap[(size_t)((mtb + mi) * nks + ks) * 64 + lane];
      acc[mi] = __builtin_amdgcn_mfma_f32_16x16x32_bf16(af, bf, acc[mi], 0, 0, 0);
    }
  }
  const int col = lane & 15;
  const int jj = col >> 2, g = col & 3;
  const int rw = g * 2304 + nt * 4 + jj;
  float bsum = b1[rw] + (b2 ? b2[rw] : 0.f);
  #pragma unroll
  for (int mi = 0; mi < 4; ++mi)
    #pragma unroll
    for (int r = 0; r < 4; ++r) {
      int m = (mtb + mi) * 16 + (lane >> 4) * 4 + r;
      int t = m >> 3, b = m & 7;
      Gx[((size_t)t * 576 + nt) * 128 + col * 8 + b] = acc[mi][r] + bsum;
    }
}

// ---------------- persistent cooperative LSTM scan ----------------
// grid = ndir*144 blocks x 256 thr (4 waves = 4 nt-columns/block).
// Each wave: holds W frags ks[0..36) resident in VGPRs, streams ks[36..72) from L3,
// keeps cell state c in registers, loops T timesteps with grid.sync() between steps.
// h is kept COMPACT (8 batch rows): per dir per parity 18432 u16 (36864 B).
// Compact layout: u16 idx = ((j>>5)*32 + ((j>>3)&3)*8 + b)*8 + (j&7)   (j = hidden idx, b = batch)
// A-frag read duplicates rows 0-7 into rows 8-15 (rows 8-15 of D unused).
__global__ __launch_bounds__(256, 2)
void lstm_scan(const unsigned short* __restrict__ Wpk0, const unsigned short* __restrict__ Wpk1,
               const float* __restrict__ Gx0, const float* __restrict__ Gx1,
               unsigned short* hbuf,
               float* __restrict__ hs0, float* __restrict__ hs1,
               int T, int blocksPerDir) {
  cg::grid_group grid = cg::this_grid();
  const int dir = blockIdx.x / blocksPerDir;
  const int cidx = blockIdx.x - dir * blocksPerDir;
  const unsigned short* __restrict__ Wpk = dir ? Wpk1 : Wpk0;
  const float* __restrict__ Gxb = dir ? Gx1 : Gx0;
  float* __restrict__ hsout = dir ? hs1 : hs0;
  unsigned short* hb = hbuf + (size_t)dir * 2 * 18432;

  const int lane = threadIdx.x & 63;
  const int wave = threadIdx.x >> 6;
  const int nt = cidx * 4 + wave;      // 0..575

  __shared__ __align__(16) unsigned short Ash[18432];   // compact h: 36864 B

  const v8s* __restrict__ Bs = (const v8s*)Wpk + (size_t)nt * 72 * 64 + lane;

  // resident weight fragments: ks 0..35
  v8s wreg[36];
  #pragma unroll
  for (int k = 0; k < 36; ++k) wreg[k] = Bs[k * 64];

  const int afoff = (lane >> 4) * 8 + (lane & 7);   // v8s index within a ks block of 32
  const int col = lane & 15;
  const int j = nt * 4 + (col >> 2);
  const int brow = (lane >> 4) * 4;
  const bool act = ((lane & 3) == 0) && (lane < 32);
  float creg[4] = {0.f, 0.f, 0.f, 0.f};            // cell state, register-resident

  for (int t = 0; t < T; ++t) {
    const unsigned short* hcur = hb + (t & 1) * 18432;
    unsigned short* hnxt = hb + ((t + 1) & 1) * 18432;

    // stage compact h into LDS (36 KB)
    for (int i = threadIdx.x; i < 2304; i += 256)
      ((float4*)Ash)[i] = ((const float4*)hcur)[i];
    __syncthreads();

    const v8s* Ap = (const v8s*)Ash;
    v4f acc0 = {0.f, 0.f, 0.f, 0.f}, acc1 = {0.f, 0.f, 0.f, 0.f};

    // prefetch first streamed chunk
    v8s bf[6], nb[6];
    #pragma unroll
    for (int u = 0; u < 6; ++u) bf[u] = Bs[(36 + u) * 64];

    // resident phase: 36 MFMAs from VGPR weights
    #pragma unroll
    for (int k = 0; k < 36; ++k) {
      v8s af = Ap[k * 32 + afoff];
      acc0 = __builtin_amdgcn_mfma_f32_16x16x32_bf16(af, wreg[k], acc0, 0, 0, 0);
    }
    // streamed phase: 36 MFMAs, 1-chunk-ahead prefetch
    #pragma unroll
    for (int c = 0; c < 6; ++c) {
      #pragma unroll
      for (int u = 0; u < 6; ++u) { if (c < 5) nb[u] = Bs[(42 + c * 6 + u) * 64]; }
      #pragma unroll
      for (int u = 0; u < 6; ++u) {
        v8s af = Ap[(36 + c * 6 + u) * 32 + afoff];
        acc1 = __builtin_amdgcn_mfma_f32_16x16x32_bf16(af, bf[u], acc1, 0, 0, 0);
      }
      #pragma unroll
      for (int u = 0; u < 6; ++u) { if (c < 5) bf[u] = nb[u]; }
    }

    // gate gather: cols col^1/col^2/col^3 hold f/g/o gates
    float vI[4], vF[4], vG[4], vO[4];
    #pragma unroll
    for (int r = 0; r < 4; ++r) {
      float a = acc0[r] + acc1[r];
      vI[r] = a;
      vF[r] = __shfl_xor(a, 1, 64);
      vG[r] = __shfl_xor(a, 2, 64);
      vO[r] = __shfl_xor(a, 3, 64);
    }
    if (act) {
      const float* Gx = Gxb + (size_t)t * 73728 + (size_t)(nt * 16 + col) * 8;
      #pragma unroll
      for (int r = 0; r < 4; ++r) {
        const int b = brow + r;
        const float gi = vI[r] + Gx[b];
        const float gf = vF[r] + Gx[8 + b];
        const float gg = vG[r] + Gx[16 + b];
        const float go = vO[r] + Gx[24 + b];
        const float si = 1.f / (1.f + expf(-gi));
        const float sf = 1.f / (1.f + expf(-gf));
        const float so = 1.f / (1.f + expf(-go));
        const float cn = sf * creg[r] + si * tanhf(gg);
        creg[r] = cn;
        const float hv = so * tanhf(cn);
        hsout[(size_t)(b * HN_ + j) * T + t] = hv;
        hnxt[((j >> 5) * 32 + ((j >> 3) & 3) * 8 + b) * 8 + (j & 7)] = f2bf(hv);
      }
    }
    __threadfence();
    grid.sync();
  }
}

// ---------------- (hs_fw + reverse(hs_bw))/2 -> tanh (or tanh only) ----------------
__global__ void combine_tanh(const float* __restrict__ hsF, const float* __restrict__ hsB,
                             float* __restrict__ gin, int t_l, int total) {
  int idx = blockIdx.x * 256 + threadIdx.x;
  if (idx >= total) return;
  int t = idx % t_l;
  float v;
  if (hsB) v = 0.5f * (hsF[idx] + hsB[idx - t + (t_l - 1 - t)]);
  else v = hsF[idx];
  gin[idx] = tanhf(v);
}

// ---------------- graph diffusion ----------------
__global__ void gc1(const float* __restrict__ in, const float* __restrict__ A,
                    float* __restrict__ out, int t_l, int total) {
  int idx = blockIdx.x * 256 + threadIdx.x;
  if (idx >= total) return;
  int t = idx % t_l;
  int w = (idx / t_l) % 144;
  int bc = idx / (t_l * 144);
  const float* src = in + (size_t)bc * 144 * t_l + t;
  float acc = 0.f;
  for (int v = 0; v < 144; ++v) acc += src[(size_t)v * t_l] * A[v * 144 + w];
  out[idx] = acc;
}

// ---------------- 1x1 conv over concat(x,x1,x2) + residual accumulate ----------------
__global__ void gc_out(const float* __restrict__ g0, const float* __restrict__ g1,
                       const float* __restrict__ g2, const float* __restrict__ Wg,
                       const float* __restrict__ bg, const float* __restrict__ prev,
                       float* __restrict__ out, int t_l, int total) {
  int idx = blockIdx.x * 256 + threadIdx.x;
  if (idx >= total) return;
  int t = idx % t_l;
  int n = (idx / t_l) % 144;
  int o = (idx / (t_l * 144)) % 16;
  int b = idx / (t_l * 144 * 16);
  float acc = bg[o];
  size_t base = ((size_t)b * 16 * 144 + n) * t_l + t;
  #pragma unroll
  for (int c = 0; c < 16; ++c) {
    size_t s = base + (size_t)c * 144 * t_l;
    acc += Wg[o * 48 + c] * g0[s] + Wg[o * 48 + 16 + c] * g1[s] + Wg[o * 48 + 32 + c] * g2[s];
  }
  if (prev) acc += prev[((size_t)(b * 16 + o) * 144 + n) * 32 + 16 + t];
  out[idx] = acc;
}

// ---------------- batchnorm over go[...,::2]; writes bf16 A-fragments for layer-1 GEMM ----------------
__global__ __launch_bounds__(256)
void bn_xt(const float* __restrict__ go, const float* __restrict__ gamma,
           const float* __restrict__ beta, unsigned short* __restrict__ xbf) {
  int c = blockIdx.x;    // channel
  __shared__ float s1[256], s2[256];
  float sum = 0.f, sq = 0.f;
  for (int i = threadIdx.x; i < 18432; i += 256) {
    int b = i / 2304; int rem = i - b * 2304; int n = rem / 16; int tt = rem & 15;
    float v = go[((size_t)(b * 16 + c) * 144 + n) * 32 + 2 * tt];
    sum += v; sq += v * v;
  }
  s1[threadIdx.x] = sum; s2[threadIdx.x] = sq; __syncthreads();
  for (int s = 128; s > 0; s >>= 1) {
    if (threadIdx.x < s) { s1[threadIdx.x] += s1[threadIdx.x + s]; s2[threadIdx.x] += s2[threadIdx.x + s]; }
    __syncthreads();
  }
  float mean = s1[0] / 18432.f;
  float var = s2[0] / 18432.f - mean * mean;
  float rs = rsqrtf(var + 1e-5f);
  float scale = gamma[c] * rs, shift = beta[c] - mean * scale;
  for (int i = threadIdx.x; i < 18432; i += 256) {
    int b = i / 2304; int rem = i - b * 2304; int n = rem / 16; int tt = rem & 15;
    float v = go[((size_t)(b * 16 + c) * 144 + n) * 32 + 2 * tt];
    int m = tt * 8 + b;
    int k = c * 144 + n;
    size_t pos = ((size_t)((m >> 4) * 72 + (k >> 5)) * 64 + ((k >> 3) & 3) * 16 + (m & 15)) * 8 + (k & 7);
    xbf[pos] = f2bf(v * scale + shift);
  }
}

// ---------------- epilogue chain ----------------
__global__ void e1_kernel(const float* __restrict__ in, const float* __restrict__ W,
                          const float* __restrict__ bias, float* __restrict__ out) {
  int idx = blockIdx.x * 256 + threadIdx.x;   // 294912
  int tt = idx & 15;
  int n = (idx >> 4) % 144;
  int o = (idx / (16 * 144)) % 16;
  int b = idx / (16 * 144 * 16);
  float acc = bias[o];
  size_t base = ((size_t)b * 16 * 144 + n) * 16 + tt;
  #pragma unroll
  for (int c = 0; c < 16; ++c) acc += in[base + (size_t)c * 144 * 16] * W[o * 16 + c];
  out[idx] = acc;
}
__global__ void e2_kernel(const float* __restrict__ in, const float* __restrict__ W,
                          const float* __restrict__ bias, float* __restrict__ out) {
  int idx = blockIdx.x * 256 + threadIdx.x;   // 589824
  int tt = idx & 15;
  int n = (idx >> 4) % 144;
  int o2 = (idx / (16 * 144)) % 32;
  int b = idx / (16 * 144 * 32);
  float acc = bias[o2];
  size_t base = ((size_t)b * 16 * 144 + n) * 16 + tt;
  #pragma unroll
  for (int o = 0; o < 16; ++o) acc += in[base + (size_t)o * 144 * 16] * W[o2 * 16 + o];
  out[idx] = acc;
}
__global__ void e3_kernel(const float* __restrict__ in, const float* __restrict__ Wlo,
                          const float* __restrict__ blo, float* __restrict__ out) {
  int idx = blockIdx.x * 256 + threadIdx.x;   // 36864
  int n = idx % 144;
  int o2 = (idx / 144) % 32;
  int b = idx / (144 * 32);
  float acc = blo[0];
  size_t base = ((size_t)(b * 32 + o2) * 144 + n) * 16;
  #pragma unroll
  for (int tt = 0; tt < 16; ++tt) acc += in[base + tt] * Wlo[tt];
  out[idx] = acc;
}
__global__ void f1_kernel(const float* __restrict__ o3, const float* __restrict__ y,
                          const float* __restrict__ ym, const float* __restrict__ W,
                          const float* __restrict__ bias, float* __restrict__ out) {
  int idx = blockIdx.x * 256 + threadIdx.x;   // 32768
  int k = idx & 127;
  int t = (idx >> 7) & 31;
  int b = idx >> 12;
  float acc = bias[k];
  size_t rb = (size_t)(b * 32 + t) * 144;
  const float* wr = W + k * 432;
  for (int n = 0; n < 144; ++n)
    acc += o3[rb + n] * wr[n] + y[rb + n] * wr[144 + n] + ym[rb + n] * wr[288 + n];
  out[idx] = acc;
}
__global__ void f2_kernel(const float* __restrict__ f1b, const float* __restrict__ W,
                          const float* __restrict__ bias, float* __restrict__ out) {
  int idx = blockIdx.x * 256 + threadIdx.x;   // 36864
  int n = idx % 144;
  int t = (idx / 144) % 32;
  int b = idx / (144 * 32);
  float acc = bias[n];
  size_t fb = (size_t)(b * 32 + t) * 128;
  const float* wr = W + n * 128;
  #pragma unroll 4
  for (int k = 0; k < 128; ++k) acc += f1b[fb + k] * wr[k];
  out[idx] = acc;
}

extern "C" void kernel_launch(void* const* d_in, const int* in_sizes, int n_in,
                              void* d_out, int out_size, void* d_ws, size_t ws_size,
                              hipStream_t stream) {
  const float* input_tensor = (const float*)d_in[0];
  const float* mask_    = (const float*)d_in[1];
  const float* input_bw = (const float*)d_in[2];
  const float* mask_bw  = (const float*)d_in[3];
  const float* y_in     = (const float*)d_in[4];
  const float* ymask    = (const float*)d_in[5];
  const float* ws_p = (const float*)d_in[6];
  const float* bs_p = (const float*)d_in[7];
  const float* wc_p = (const float*)d_in[8];
  const float* bc_p = (const float*)d_in[9];
  const float* nv1 = (const float*)d_in[10];
  const float* nv2 = (const float*)d_in[11];
  const float* Wih_fw = (const float*)d_in[12];
  const float* Whh_fw = (const float*)d_in[13];
  const float* bih_fw = (const float*)d_in[14];
  const float* bhh_fw = (const float*)d_in[15];
  const float* Wih_bw = (const float*)d_in[16];
  const float* Whh_bw = (const float*)d_in[17];
  const float* bih_bw = (const float*)d_in[18];
  const float* bhh_bw = (const float*)d_in[19];
  const float* Wg   = (const float*)d_in[20];
  const float* bg   = (const float*)d_in[21];
  const float* gam  = (const float*)d_in[22];
  const float* bet  = (const float*)d_in[23];
  const float* W_end1 = (const float*)d_in[24];
  const float* b_end1 = (const float*)d_in[25];
  const float* W_end2 = (const float*)d_in[26];
  const float* b_end2 = (const float*)d_in[27];
  const float* W_lo = (const float*)d_in[28];
  const float* b_lo = (const float*)d_in[29];
  const float* W_f1 = (const float*)d_in[30];
  const float* b_f1 = (const float*)d_in[31];
  const float* W_f2 = (const float*)d_in[32];
  const float* b_f2 = (const float*)d_in[33];

  char* base = (char*)d_ws;
  size_t off = 0;
  auto alloc = [&](size_t bytes) -> char* {
    char* p = base + off;
    off += (bytes + 255) & ~(size_t)255;
    return p;
  };
  float* adp   = (float*)alloc(144 * 144 * 4);
  unsigned short* Weffpk = (unsigned short*)alloc((size_t)2 * 2654208 * 2);  // 10.6 MB
  float* beff  = (float*)alloc(2 * G4_ * 4);
  unsigned short* acatf  = (unsigned short*)alloc((size_t)2 * 73728 * 2);
  float* GxF   = (float*)alloc((size_t)32 * 73728 * 4);   // 9.44 MB
  float* GxB   = (float*)alloc((size_t)32 * 73728 * 4);
  char*  hz    = alloc(147456 + 73728);                   // compact h dbl-buffers (zeroed)
  float* hsF   = (float*)alloc((size_t)589824 * 4);
  float* hsB   = (float*)alloc((size_t)589824 * 4);
  float* hsL   = (float*)alloc((size_t)294912 * 4);
  float* gin   = (float*)alloc((size_t)589824 * 4);
  float* x1b   = (float*)alloc((size_t)589824 * 4);
  float* x2b   = (float*)alloc((size_t)589824 * 4);
  float* out0  = (float*)alloc((size_t)589824 * 4);
  float* out1  = (float*)alloc((size_t)294912 * 4);
  unsigned short* xbf = (unsigned short*)alloc((size_t)294912 * 2);
  float* tmp1  = (float*)alloc((size_t)294912 * 4);
  float* tmp2  = (float*)alloc((size_t)589824 * 4);
  float* out3  = (float*)alloc((size_t)36864 * 4);
  float* f1b   = (float*)alloc((size_t)32768 * 4);
  unsigned short* P0 = (unsigned short*)alloc((size_t)2654208 * 8 * 2);  // 42.5 MB
  unsigned short* P1 = (unsigned short*)alloc((size_t)2654208 * 8 * 2);

  unsigned short* hbuf0 = (unsigned short*)hz;            // layer-0: [dir][2][18432]
  unsigned short* hbufL = (unsigned short*)(hz + 147456); // layer-1: [2][18432]

  hipMemsetAsync(hz, 0, 147456 + 73728, stream);

  adp_kernel<<<144, 256, 0, stream>>>(nv1, nv2, adp);
  eff_weights<<<dim3(G4_, 2), 256, 0, stream>>>(Wih_fw, Wih_bw, bih_fw, bhh_fw, bih_bw, bhh_bw,
                                                ws_p, bs_p, wc_p, bc_p, Weffpk, beff);
  build_acat_frag<<<72, 256, 0, stream>>>(input_tensor, mask_, input_bw, mask_bw, acatf);
  gemm_frag<<<dim3(576, 4), 64, 0, stream>>>(acatf, Weffpk, beff, nullptr, GxF, 9);
  gemm_frag<<<dim3(576, 4), 64, 0, stream>>>(acatf + 73728, Weffpk + 2654208, beff + G4_, nullptr, GxB, 9);
  pack_whh<<<10368, 256, 0, stream>>>(Whh_fw, P0);
  pack_whh<<<10368, 256, 0, stream>>>(Whh_bw, P1);

  // ---- layer-0 scan: single persistent cooperative kernel (fw + bw) ----
  {
    const unsigned short* aW0 = P0; const unsigned short* aW1 = P1;
    const float* aG0 = GxF; const float* aG1 = GxB;
    unsigned short* ah = hbuf0;
    float* ahs0 = hsF; float* ahs1 = hsB;
    int aT = 32, aB = 144;
    void* args[] = {&aW0, &aW1, &aG0, &aG1, &ah, &ahs0, &ahs1, &aT, &aB};
    hipLaunchCooperativeKernel((void*)lstm_scan, dim3(288), dim3(256), args, 0, stream);
  }

  combine_tanh<<<2304, 256, 0, stream>>>(hsF, hsB, gin, 32, 589824);
  gc1<<<2304, 256, 0, stream>>>(gin, adp, x1b, 32, 589824);
  gc1<<<2304, 256, 0, stream>>>(x1b, adp, x2b, 32, 589824);
  gc_out<<<2304, 256, 0, stream>>>(gin, x1b, x2b, Wg, bg, nullptr, out0, 32, 589824);
  bn_xt<<<16, 256, 0, stream>>>(out0, gam, bet, xbf);

  const size_t WL1_off = (size_t)G4_ * HN_;
  pack_whh<<<10368, 256, 0, stream>>>(Wih_fw + WL1_off, P1);   // layer-1 input weights
  gemm_frag<<<dim3(576, 2), 64, 0, stream>>>(xbf, P1, bih_fw + G4_, bhh_fw + G4_, GxF, 72);
  pack_whh<<<10368, 256, 0, stream>>>(Whh_fw + WL1_off, P0);   // layer-1 recurrent weights

  // ---- layer-1 scan: persistent cooperative kernel (single dir) ----
  {
    const unsigned short* aW0 = P0; const unsigned short* aW1 = P0;
    const float* aG0 = GxF; const float* aG1 = GxF;
    unsigned short* ah = hbufL;
    float* ahs0 = hsL; float* ahs1 = hsL;
    int aT = 16, aB = 144;
    void* args[] = {&aW0, &aW1, &aG0, &aG1, &ah, &ahs0, &ahs1, &aT, &aB};
    hipLaunchCooperativeKernel((void*)lstm_scan, dim3(144), dim3(256), args, 0, stream);
  }

  combine_tanh<<<1152, 256, 0, stream>>>(hsL, nullptr, gin, 16, 294912);
  gc1<<<1152, 256, 0, stream>>>(gin, adp, x1b, 16, 294912);
  gc1<<<1152, 256, 0, stream>>>(x1b, adp, x2b, 16, 294912);
  gc_out<<<1152, 256, 0, stream>>>(gin, x1b, x2b, Wg + 16 * 48, bg + 16, out0, out1, 16, 294912);

  e1_kernel<<<1152, 256, 0, stream>>>(out1, W_end1, b_end1, tmp1);
  e2_kernel<<<2304, 256, 0, stream>>>(tmp1, W_end2, b_end2, tmp2);
  e3_kernel<<<144, 256, 0, stream>>>(tmp2, W_lo, b_lo, out3);
  f1_kernel<<<128, 256, 0, stream>>>(out3, y_in, ymask, W_f1, b_f1, f1b);
  f2_kernel<<<144, 256, 0, stream>>>(f1b, W_f2, b_f2, (float*)d_out);
}

// Round 2
// 1486.572 us; speedup vs baseline: 2.6063x; 2.6063x over previous
//
#include <hip/hip_runtime.h>
#include <cstdint>
#include <cstddef>

#define HN_ 2304
#define G4_ 9216

typedef __attribute__((ext_vector_type(8))) short v8s;
typedef __attribute__((ext_vector_type(4))) float v4f;

__device__ __forceinline__ unsigned short f2bf(float x) {
  union { float f; unsigned int i; } v; v.f = x;
  unsigned int r = (v.i + 0x7fffu + ((v.i >> 16) & 1u)) >> 16;
  return (unsigned short)r;
}

// ---------------- adp = softmax(relu(nv1@nv2), axis=1) ----------------
__global__ __launch_bounds__(256) void adp_kernel(const float* __restrict__ nv1,
                                                  const float* __restrict__ nv2,
                                                  float* __restrict__ adp) {
  int i = blockIdx.x;
  int j = threadIdx.x;
  __shared__ float sm[256];
  float r = 0.f, v = -1e30f;
  if (j < 144) {
    for (int k = 0; k < 10; ++k) r += nv1[i * 10 + k] * nv2[k * 144 + j];
    r = fmaxf(r, 0.f);
    v = r;
  }
  sm[j] = v; __syncthreads();
  for (int s = 128; s > 0; s >>= 1) { if (j < s) sm[j] = fmaxf(sm[j], sm[j + s]); __syncthreads(); }
  float mx = sm[0]; __syncthreads();
  float e = (j < 144) ? expf(r - mx) : 0.f;
  sm[j] = e; __syncthreads();
  for (int s = 128; s > 0; s >>= 1) { if (j < s) sm[j] += sm[j + s]; __syncthreads(); }
  float sum = sm[0];
  if (j < 144) adp[i * 144 + j] = e / sum;
}

// ---------------- layer-0 effective input weights, written as packed bf16 frags ----------------
__global__ __launch_bounds__(256)
void eff_weights(const float* __restrict__ WihF, const float* __restrict__ WihB,
                 const float* __restrict__ bihF, const float* __restrict__ bhhF,
                 const float* __restrict__ bihB, const float* __restrict__ bhhB,
                 const float* __restrict__ ws, const float* __restrict__ bs,
                 const float* __restrict__ wc, const float* __restrict__ bc,
                 unsigned short* __restrict__ Wpk, float* __restrict__ beff) {
  const int r = blockIdx.x, dir = blockIdx.y;
  const float* W = dir ? WihB : WihF;
  __shared__ float red[256];
  const int n = threadIdx.x;
  float spb = 0.f;
  if (n < 144) {
    float sws = 0.f, swc = 0.f;
    #pragma unroll
    for (int c = 0; c < 16; ++c) {
      float w = W[(size_t)r * HN_ + c * 144 + n];
      sws += w * ws[c];
      swc += w * wc[c];
      spb += w * (bs[c] + bc[c]);
    }
    const int rm = r % 2304;
    const int g = r / 2304;
    const int nt = rm >> 2, col = (rm & 3) * 4 + g;
    unsigned short* outp = Wpk + (size_t)dir * 2654208;
    int k = n;
    outp[((size_t)(nt * 9 + (k >> 5)) * 64 + ((k >> 3) & 3) * 16 + col) * 8 + (k & 7)] = f2bf(sws);
    k = 144 + n;
    outp[((size_t)(nt * 9 + (k >> 5)) * 64 + ((k >> 3) & 3) * 16 + col) * 8 + (k & 7)] = f2bf(swc);
  }
  red[n] = spb; __syncthreads();
  for (int s = 128; s > 0; s >>= 1) { if (n < s) red[n] += red[n + s]; __syncthreads(); }
  if (n == 0) {
    const float* bih = dir ? bihB : bihF;
    const float* bhh = dir ? bhhB : bhhF;
    beff[dir * G4_ + r] = red[0] + bih[r] + bhh[r];
  }
}

// ---------------- build A fragments for layer-0 input GEMM (bf16) ----------------
__global__ void build_acat_frag(const float* __restrict__ inF, const float* __restrict__ mF,
                                const float* __restrict__ inB, const float* __restrict__ mB,
                                unsigned short* __restrict__ out) {
  int idx = blockIdx.x * 256 + threadIdx.x;   // 18432 frags total
  int lane = idx & 63;
  int ks = (idx >> 6) % 9;
  int mt = (idx / (64 * 9)) % 16;
  int dir = idx / (64 * 9 * 16);
  int m = mt * 16 + (lane & 15);
  int k = ks * 32 + (lane >> 4) * 8;
  int t = m >> 3, b = m & 7;
  const float* src; int kk = k;
  if (k < 144) src = dir ? inB : inF;
  else { src = dir ? mB : mF; kk = k - 144; }
  const float* p = src + ((size_t)b * 32 + t) * 144 + kk;
  v8s o;
  #pragma unroll
  for (int e = 0; e < 8; ++e) o[e] = (short)f2bf(p[e]);
  ((v8s*)out)[idx] = o;
}

// ---------------- pack a [9216 x 2304] weight matrix into gate-interleaved bf16 frags ----------------
__global__ void pack_whh(const float* __restrict__ W, unsigned short* __restrict__ out) {
  int idx = blockIdx.x * 256 + threadIdx.x;   // 576*72*64 = 2,654,208
  int lane = idx & 63;
  int ks = (idx >> 6) % 72;
  int nt = idx / (64 * 72);
  int col = lane & 15, q = lane >> 4;
  int r = (col & 3) * 2304 + nt * 4 + (col >> 2);
  int k = ks * 32 + q * 8;
  const float* src = W + (size_t)r * 2304 + k;
  float4 v0 = *(const float4*)src;
  float4 v1 = *(const float4*)(src + 4);
  v8s o;
  o[0] = (short)f2bf(v0.x); o[1] = (short)f2bf(v0.y);
  o[2] = (short)f2bf(v0.z); o[3] = (short)f2bf(v0.w);
  o[4] = (short)f2bf(v1.x); o[5] = (short)f2bf(v1.y);
  o[6] = (short)f2bf(v1.z); o[7] = (short)f2bf(v1.w);
  ((v8s*)out)[idx] = o;
}

// ---------------- MFMA GEMM over fragment-packed operands; writes Gx[t][nt][col][b] ----------------
__global__ __launch_bounds__(64)
void gemm_frag(const unsigned short* __restrict__ Apk, const unsigned short* __restrict__ Wpk,
               const float* __restrict__ b1, const float* __restrict__ b2,
               float* __restrict__ Gx, int nks) {
  const int lane = threadIdx.x;
  const int nt = blockIdx.x;
  const int mtb = blockIdx.y * 4;
  v4f acc[4] = {};
  const v8s* Bp = (const v8s*)Wpk + (size_t)nt * nks * 64;
  const v8s* Ap = (const v8s*)Apk;
  for (int ks = 0; ks < nks; ++ks) {
    v8s bf = Bp[ks * 64 + lane];
    #pragma unroll
    for (int mi = 0; mi < 4; ++mi) {
      v8s af = Ap[(size_t)((mtb + mi) * nks + ks) * 64 + lane];
      acc[mi] = __builtin_amdgcn_mfma_f32_16x16x32_bf16(af, bf, acc[mi], 0, 0, 0);
    }
  }
  const int col = lane & 15;
  const int jj = col >> 2, g = col & 3;
  const int rw = g * 2304 + nt * 4 + jj;
  float bsum = b1[rw] + (b2 ? b2[rw] : 0.f);
  #pragma unroll
  for (int mi = 0; mi < 4; ++mi)
    #pragma unroll
    for (int r = 0; r < 4; ++r) {
      int m = (mtb + mi) * 16 + (lane >> 4) * 4 + r;
      int t = m >> 3, b = m & 7;
      Gx[((size_t)t * 576 + nt) * 128 + col * 8 + b] = acc[mi][r] + bsum;
    }
}

// ---------------- one LSTM timestep, 4-way split-K MFMA ----------------
// grid (576, ndir), block 256 (4 waves). Block = one nt column; wave w covers ks in [w*18, w*18+18).
// h kept COMPACT (8 batch rows): per dir per parity 18432 u16 (36864 B), read direct from global (L2-hit).
// Compact layout: u16 idx = (ks*32 + q*8 + b)*8 + e  for hidden j = ks*32 + q*8 + e, batch b.
// A-frag lanes 8-15 duplicate rows 0-7 (D rows 8-15 unused).
__global__ __launch_bounds__(256, 4)
void lstm_step(const unsigned short* __restrict__ Wpk0, const unsigned short* __restrict__ Wpk1,
               const float* __restrict__ Gx0, const float* __restrict__ Gx1,
               const unsigned short* __restrict__ hin0, const unsigned short* __restrict__ hin1,
               unsigned short* __restrict__ hout0, unsigned short* __restrict__ hout1,
               float* __restrict__ c0, float* __restrict__ c1,
               float* __restrict__ hs0, float* __restrict__ hs1,
               int t, int T) {
  const int dir = blockIdx.y;
  const unsigned short* __restrict__ Wpk = dir ? Wpk1 : Wpk0;
  const float* __restrict__ Gxb = dir ? Gx1 : Gx0;
  const unsigned short* __restrict__ hin = dir ? hin1 : hin0;
  unsigned short* __restrict__ hout = dir ? hout1 : hout0;
  float* __restrict__ cb = dir ? c1 : c0;
  float* __restrict__ hsout = dir ? hs1 : hs0;

  const int lane = threadIdx.x & 63;
  const int wave = threadIdx.x >> 6;
  const int nt = blockIdx.x;

  const int afoff = (lane >> 4) * 8 + (lane & 7);   // v8s index within one ks block of 32
  const v8s* __restrict__ Aq = (const v8s*)hin + (size_t)(wave * 18) * 32 + afoff;
  const v8s* __restrict__ Bq = (const v8s*)Wpk + (size_t)nt * 72 * 64 + (size_t)(wave * 18) * 64 + lane;

  v4f acc = {0.f, 0.f, 0.f, 0.f};
  #pragma unroll
  for (int k = 0; k < 18; ++k) {
    v8s af = Aq[k * 32];
    v8s bf = Bq[k * 64];
    acc = __builtin_amdgcn_mfma_f32_16x16x32_bf16(af, bf, acc, 0, 0, 0);
  }

  __shared__ v4f red[3][64];
  if (wave) red[wave - 1][lane] = acc;
  __syncthreads();
  if (wave == 0) {
    acc += red[0][lane];
    acc += red[1][lane];
    acc += red[2][lane];

    // gate gather: cols col^1/col^2/col^3 hold f/g/o gates
    float vI[4], vF[4], vG[4], vO[4];
    #pragma unroll
    for (int r = 0; r < 4; ++r) {
      float a = acc[r];
      vI[r] = a;
      vF[r] = __shfl_xor(a, 1, 64);
      vG[r] = __shfl_xor(a, 2, 64);
      vO[r] = __shfl_xor(a, 3, 64);
    }
    const int col = lane & 15;
    if ((lane & 3) == 0 && lane < 32) {
      const int j = nt * 4 + (col >> 2);
      const int brow = (lane >> 4) * 4;
      const float* Gx = Gxb + (size_t)t * 73728 + (size_t)(nt * 16 + col) * 8;
      #pragma unroll
      for (int r = 0; r < 4; ++r) {
        const int b = brow + r;
        const float gi = vI[r] + Gx[b];
        const float gf = vF[r] + Gx[8 + b];
        const float gg = vG[r] + Gx[16 + b];
        const float go = vO[r] + Gx[24 + b];
        const float si = 1.f / (1.f + expf(-gi));
        const float sf = 1.f / (1.f + expf(-gf));
        const float so = 1.f / (1.f + expf(-go));
        const float cn = sf * cb[b * HN_ + j] + si * tanhf(gg);
        cb[b * HN_ + j] = cn;
        const float hv = so * tanhf(cn);
        hsout[(size_t)(b * HN_ + j) * T + t] = hv;
        hout[((j >> 5) * 32 + ((j >> 3) & 3) * 8 + b) * 8 + (j & 7)] = f2bf(hv);
      }
    }
  }
}

// ---------------- (hs_fw + reverse(hs_bw))/2 -> tanh (or tanh only) ----------------
__global__ void combine_tanh(const float* __restrict__ hsF, const float* __restrict__ hsB,
                             float* __restrict__ gin, int t_l, int total) {
  int idx = blockIdx.x * 256 + threadIdx.x;
  if (idx >= total) return;
  int t = idx % t_l;
  float v;
  if (hsB) v = 0.5f * (hsF[idx] + hsB[idx - t + (t_l - 1 - t)]);
  else v = hsF[idx];
  gin[idx] = tanhf(v);
}

// ---------------- graph diffusion ----------------
__global__ void gc1(const float* __restrict__ in, const float* __restrict__ A,
                    float* __restrict__ out, int t_l, int total) {
  int idx = blockIdx.x * 256 + threadIdx.x;
  if (idx >= total) return;
  int t = idx % t_l;
  int w = (idx / t_l) % 144;
  int bc = idx / (t_l * 144);
  const float* src = in + (size_t)bc * 144 * t_l + t;
  float acc = 0.f;
  for (int v = 0; v < 144; ++v) acc += src[(size_t)v * t_l] * A[v * 144 + w];
  out[idx] = acc;
}

// ---------------- 1x1 conv over concat(x,x1,x2) + residual accumulate ----------------
__global__ void gc_out(const float* __restrict__ g0, const float* __restrict__ g1,
                       const float* __restrict__ g2, const float* __restrict__ Wg,
                       const float* __restrict__ bg, const float* __restrict__ prev,
                       float* __restrict__ out, int t_l, int total) {
  int idx = blockIdx.x * 256 + threadIdx.x;
  if (idx >= total) return;
  int t = idx % t_l;
  int n = (idx / t_l) % 144;
  int o = (idx / (t_l * 144)) % 16;
  int b = idx / (t_l * 144 * 16);
  float acc = bg[o];
  size_t base = ((size_t)b * 16 * 144 + n) * t_l + t;
  #pragma unroll
  for (int c = 0; c < 16; ++c) {
    size_t s = base + (size_t)c * 144 * t_l;
    acc += Wg[o * 48 + c] * g0[s] + Wg[o * 48 + 16 + c] * g1[s] + Wg[o * 48 + 32 + c] * g2[s];
  }
  if (prev) acc += prev[((size_t)(b * 16 + o) * 144 + n) * 32 + 16 + t];
  out[idx] = acc;
}

// ---------------- batchnorm over go[...,::2]; writes bf16 A-fragments for layer-1 GEMM ----------------
__global__ __launch_bounds__(256)
void bn_xt(const float* __restrict__ go, const float* __restrict__ gamma,
           const float* __restrict__ beta, unsigned short* __restrict__ xbf) {
  int c = blockIdx.x;    // channel
  __shared__ float s1[256], s2[256];
  float sum = 0.f, sq = 0.f;
  for (int i = threadIdx.x; i < 18432; i += 256) {
    int b = i / 2304; int rem = i - b * 2304; int n = rem / 16; int tt = rem & 15;
    float v = go[((size_t)(b * 16 + c) * 144 + n) * 32 + 2 * tt];
    sum += v; sq += v * v;
  }
  s1[threadIdx.x] = sum; s2[threadIdx.x] = sq; __syncthreads();
  for (int s = 128; s > 0; s >>= 1) {
    if (threadIdx.x < s) { s1[threadIdx.x] += s1[threadIdx.x + s]; s2[threadIdx.x] += s2[threadIdx.x + s]; }
    __syncthreads();
  }
  float mean = s1[0] / 18432.f;
  float var = s2[0] / 18432.f - mean * mean;
  float rs = rsqrtf(var + 1e-5f);
  float scale = gamma[c] * rs, shift = beta[c] - mean * scale;
  for (int i = threadIdx.x; i < 18432; i += 256) {
    int b = i / 2304; int rem = i - b * 2304; int n = rem / 16; int tt = rem & 15;
    float v = go[((size_t)(b * 16 + c) * 144 + n) * 32 + 2 * tt];
    int m = tt * 8 + b;
    int k = c * 144 + n;
    size_t pos = ((size_t)((m >> 4) * 72 + (k >> 5)) * 64 + ((k >> 3) & 3) * 16 + (m & 15)) * 8 + (k & 7);
    xbf[pos] = f2bf(v * scale + shift);
  }
}

// ---------------- epilogue chain ----------------
__global__ void e1_kernel(const float* __restrict__ in, const float* __restrict__ W,
                          const float* __restrict__ bias, float* __restrict__ out) {
  int idx = blockIdx.x * 256 + threadIdx.x;   // 294912
  int tt = idx & 15;
  int n = (idx >> 4) % 144;
  int o = (idx / (16 * 144)) % 16;
  int b = idx / (16 * 144 * 16);
  float acc = bias[o];
  size_t base = ((size_t)b * 16 * 144 + n) * 16 + tt;
  #pragma unroll
  for (int c = 0; c < 16; ++c) acc += in[base + (size_t)c * 144 * 16] * W[o * 16 + c];
  out[idx] = acc;
}
__global__ void e2_kernel(const float* __restrict__ in, const float* __restrict__ W,
                          const float* __restrict__ bias, float* __restrict__ out) {
  int idx = blockIdx.x * 256 + threadIdx.x;   // 589824
  int tt = idx & 15;
  int n = (idx >> 4) % 144;
  int o2 = (idx / (16 * 144)) % 32;
  int b = idx / (16 * 144 * 32);
  float acc = bias[o2];
  size_t base = ((size_t)b * 16 * 144 + n) * 16 + tt;
  #pragma unroll
  for (int o = 0; o < 16; ++o) acc += in[base + (size_t)o * 144 * 16] * W[o2 * 16 + o];
  out[idx] = acc;
}
__global__ void e3_kernel(const float* __restrict__ in, const float* __restrict__ Wlo,
                          const float* __restrict__ blo, float* __restrict__ out) {
  int idx = blockIdx.x * 256 + threadIdx.x;   // 36864
  int n = idx % 144;
  int o2 = (idx / 144) % 32;
  int b = idx / (144 * 32);
  float acc = blo[0];
  size_t base = ((size_t)(b * 32 + o2) * 144 + n) * 16;
  #pragma unroll
  for (int tt = 0; tt < 16; ++tt) acc += in[base + tt] * Wlo[tt];
  out[idx] = acc;
}
__global__ void f1_kernel(const float* __restrict__ o3, const float* __restrict__ y,
                          const float* __restrict__ ym, const float* __restrict__ W,
                          const float* __restrict__ bias, float* __restrict__ out) {
  int idx = blockIdx.x * 256 + threadIdx.x;   // 32768
  int k = idx & 127;
  int t = (idx >> 7) & 31;
  int b = idx >> 12;
  float acc = bias[k];
  size_t rb = (size_t)(b * 32 + t) * 144;
  const float* wr = W + k * 432;
  for (int n = 0; n < 144; ++n)
    acc += o3[rb + n] * wr[n] + y[rb + n] * wr[144 + n] + ym[rb + n] * wr[288 + n];
  out[idx] = acc;
}
__global__ void f2_kernel(const float* __restrict__ f1b, const float* __restrict__ W,
                          const float* __restrict__ bias, float* __restrict__ out) {
  int idx = blockIdx.x * 256 + threadIdx.x;   // 36864
  int n = idx % 144;
  int t = (idx / 144) % 32;
  int b = idx / (144 * 32);
  float acc = bias[n];
  size_t fb = (size_t)(b * 32 + t) * 128;
  const float* wr = W + n * 128;
  #pragma unroll 4
  for (int k = 0; k < 128; ++k) acc += f1b[fb + k] * wr[k];
  out[idx] = acc;
}

extern "C" void kernel_launch(void* const* d_in, const int* in_sizes, int n_in,
                              void* d_out, int out_size, void* d_ws, size_t ws_size,
                              hipStream_t stream) {
  const float* input_tensor = (const float*)d_in[0];
  const float* mask_    = (const float*)d_in[1];
  const float* input_bw = (const float*)d_in[2];
  const float* mask_bw  = (const float*)d_in[3];
  const float* y_in     = (const float*)d_in[4];
  const float* ymask    = (const float*)d_in[5];
  const float* ws_p = (const float*)d_in[6];
  const float* bs_p = (const float*)d_in[7];
  const float* wc_p = (const float*)d_in[8];
  const float* bc_p = (const float*)d_in[9];
  const float* nv1 = (const float*)d_in[10];
  const float* nv2 = (const float*)d_in[11];
  const float* Wih_fw = (const float*)d_in[12];
  const float* Whh_fw = (const float*)d_in[13];
  const float* bih_fw = (const float*)d_in[14];
  const float* bhh_fw = (const float*)d_in[15];
  const float* Wih_bw = (const float*)d_in[16];
  const float* Whh_bw = (const float*)d_in[17];
  const float* bih_bw = (const float*)d_in[18];
  const float* bhh_bw = (const float*)d_in[19];
  const float* Wg   = (const float*)d_in[20];
  const float* bg   = (const float*)d_in[21];
  const float* gam  = (const float*)d_in[22];
  const float* bet  = (const float*)d_in[23];
  const float* W_end1 = (const float*)d_in[24];
  const float* b_end1 = (const float*)d_in[25];
  const float* W_end2 = (const float*)d_in[26];
  const float* b_end2 = (const float*)d_in[27];
  const float* W_lo = (const float*)d_in[28];
  const float* b_lo = (const float*)d_in[29];
  const float* W_f1 = (const float*)d_in[30];
  const float* b_f1 = (const float*)d_in[31];
  const float* W_f2 = (const float*)d_in[32];
  const float* b_f2 = (const float*)d_in[33];

  char* base = (char*)d_ws;
  size_t off = 0;
  auto alloc = [&](size_t bytes) -> char* {
    char* p = base + off;
    off += (bytes + 255) & ~(size_t)255;
    return p;
  };
  float* adp   = (float*)alloc(144 * 144 * 4);
  unsigned short* Weffpk = (unsigned short*)alloc((size_t)2 * 2654208 * 2);  // 10.6 MB
  float* beff  = (float*)alloc(2 * G4_ * 4);
  unsigned short* acatf  = (unsigned short*)alloc((size_t)2 * 73728 * 2);
  float* GxF   = (float*)alloc((size_t)32 * 73728 * 4);   // 9.44 MB
  float* GxB   = (float*)alloc((size_t)32 * 73728 * 4);
  char*  hz    = alloc(442368);                            // compact h dbl-bufs + c bufs (zeroed)
  float* hsF   = (float*)alloc((size_t)589824 * 4);
  float* hsB   = (float*)alloc((size_t)589824 * 4);
  float* hsL   = (float*)alloc((size_t)294912 * 4);
  float* gin   = (float*)alloc((size_t)589824 * 4);
  float* x1b   = (float*)alloc((size_t)589824 * 4);
  float* x2b   = (float*)alloc((size_t)589824 * 4);
  float* out0  = (float*)alloc((size_t)589824 * 4);
  float* out1  = (float*)alloc((size_t)294912 * 4);
  unsigned short* xbf = (unsigned short*)alloc((size_t)294912 * 2);
  float* tmp1  = (float*)alloc((size_t)294912 * 4);
  float* tmp2  = (float*)alloc((size_t)589824 * 4);
  float* out3  = (float*)alloc((size_t)36864 * 4);
  float* f1b   = (float*)alloc((size_t)32768 * 4);
  unsigned short* P0 = (unsigned short*)alloc((size_t)2654208 * 8 * 2);  // 42.5 MB
  unsigned short* P1 = (unsigned short*)alloc((size_t)2654208 * 8 * 2);

  unsigned short* hF[2] = {(unsigned short*)hz,            (unsigned short*)(hz + 36864)};
  unsigned short* hB[2] = {(unsigned short*)(hz + 73728),  (unsigned short*)(hz + 110592)};
  unsigned short* hL[2] = {(unsigned short*)(hz + 147456), (unsigned short*)(hz + 184320)};
  float* cF = (float*)(hz + 221184);
  float* cB = (float*)(hz + 294912);
  float* cL = (float*)(hz + 368640);

  hipMemsetAsync(hz, 0, 442368, stream);

  adp_kernel<<<144, 256, 0, stream>>>(nv1, nv2, adp);
  eff_weights<<<dim3(G4_, 2), 256, 0, stream>>>(Wih_fw, Wih_bw, bih_fw, bhh_fw, bih_bw, bhh_bw,
                                                ws_p, bs_p, wc_p, bc_p, Weffpk, beff);
  build_acat_frag<<<72, 256, 0, stream>>>(input_tensor, mask_, input_bw, mask_bw, acatf);
  gemm_frag<<<dim3(576, 4), 64, 0, stream>>>(acatf, Weffpk, beff, nullptr, GxF, 9);
  gemm_frag<<<dim3(576, 4), 64, 0, stream>>>(acatf + 73728, Weffpk + 2654208, beff + G4_, nullptr, GxB, 9);
  pack_whh<<<10368, 256, 0, stream>>>(Whh_fw, P0);
  pack_whh<<<10368, 256, 0, stream>>>(Whh_bw, P1);

  // ---- layer-0 scan (fw + bw concurrently), 4-way split-K per step ----
  for (int t = 0; t < 32; ++t) {
    lstm_step<<<dim3(576, 2), 256, 0, stream>>>(
        P0, P1, GxF, GxB,
        hF[t & 1], hB[t & 1], hF[(t + 1) & 1], hB[(t + 1) & 1],
        cF, cB, hsF, hsB, t, 32);
  }

  combine_tanh<<<2304, 256, 0, stream>>>(hsF, hsB, gin, 32, 589824);
  gc1<<<2304, 256, 0, stream>>>(gin, adp, x1b, 32, 589824);
  gc1<<<2304, 256, 0, stream>>>(x1b, adp, x2b, 32, 589824);
  gc_out<<<2304, 256, 0, stream>>>(gin, x1b, x2b, Wg, bg, nullptr, out0, 32, 589824);
  bn_xt<<<16, 256, 0, stream>>>(out0, gam, bet, xbf);

  const size_t WL1_off = (size_t)G4_ * HN_;
  pack_whh<<<10368, 256, 0, stream>>>(Wih_fw + WL1_off, P1);   // layer-1 input weights
  gemm_frag<<<dim3(576, 2), 64, 0, stream>>>(xbf, P1, bih_fw + G4_, bhh_fw + G4_, GxF, 72);
  pack_whh<<<10368, 256, 0, stream>>>(Whh_fw + WL1_off, P0);   // layer-1 recurrent weights

  // ---- layer-1 scan ----
  for (int t = 0; t < 16; ++t) {
    lstm_step<<<dim3(576, 1), 256, 0, stream>>>(
        P0, P0, GxF, GxF,
        hL[t & 1], hL[t & 1], hL[(t + 1) & 1], hL[(t + 1) & 1],
        cL, cL, hsL, hsL, t, 16);
  }

  combine_tanh<<<1152, 256, 0, stream>>>(hsL, nullptr, gin, 16, 294912);
  gc1<<<1152, 256, 0, stream>>>(gin, adp, x1b, 16, 294912);
  gc1<<<1152, 256, 0, stream>>>(x1b, adp, x2b, 16, 294912);
  gc_out<<<1152, 256, 0, stream>>>(gin, x1b, x2b, Wg + 16 * 48, bg + 16, out0, out1, 16, 294912);

  e1_kernel<<<1152, 256, 0, stream>>>(out1, W_end1, b_end1, tmp1);
  e2_kernel<<<2304, 256, 0, stream>>>(tmp1, W_end2, b_end2, tmp2);
  e3_kernel<<<144, 256, 0, stream>>>(tmp2, W_lo, b_lo, out3);
  f1_kernel<<<128, 256, 0, stream>>>(out3, y_in, ymask, W_f1, b_f1, f1b);
  f2_kernel<<<144, 256, 0, stream>>>(f1b, W_f2, b_f2, (float*)d_out);
}

// Round 3
// 1434.188 us; speedup vs baseline: 2.7015x; 1.0365x over previous
//
#include <hip/hip_runtime.h>
#include <cstdint>
#include <cstddef>

#define HN_ 2304
#define G4_ 9216

typedef __attribute__((ext_vector_type(8))) short v8s;
typedef __attribute__((ext_vector_type(4))) float v4f;

__device__ __forceinline__ unsigned short f2bf(float x) {
  union { float f; unsigned int i; } v; v.f = x;
  unsigned int r = (v.i + 0x7fffu + ((v.i >> 16) & 1u)) >> 16;
  return (unsigned short)r;
}

// ---------------- adp = softmax(relu(nv1@nv2), axis=1) ----------------
__global__ __launch_bounds__(256) void adp_kernel(const float* __restrict__ nv1,
                                                  const float* __restrict__ nv2,
                                                  float* __restrict__ adp) {
  int i = blockIdx.x;
  int j = threadIdx.x;
  __shared__ float sm[256];
  float r = 0.f, v = -1e30f;
  if (j < 144) {
    for (int k = 0; k < 10; ++k) r += nv1[i * 10 + k] * nv2[k * 144 + j];
    r = fmaxf(r, 0.f);
    v = r;
  }
  sm[j] = v; __syncthreads();
  for (int s = 128; s > 0; s >>= 1) { if (j < s) sm[j] = fmaxf(sm[j], sm[j + s]); __syncthreads(); }
  float mx = sm[0]; __syncthreads();
  float e = (j < 144) ? expf(r - mx) : 0.f;
  sm[j] = e; __syncthreads();
  for (int s = 128; s > 0; s >>= 1) { if (j < s) sm[j] += sm[j + s]; __syncthreads(); }
  float sum = sm[0];
  if (j < 144) adp[i * 144 + j] = e / sum;
}

// ---------------- layer-0 effective input weights, written as packed bf16 frags ----------------
__global__ __launch_bounds__(256)
void eff_weights(const float* __restrict__ WihF, const float* __restrict__ WihB,
                 const float* __restrict__ bihF, const float* __restrict__ bhhF,
                 const float* __restrict__ bihB, const float* __restrict__ bhhB,
                 const float* __restrict__ ws, const float* __restrict__ bs,
                 const float* __restrict__ wc, const float* __restrict__ bc,
                 unsigned short* __restrict__ Wpk, float* __restrict__ beff) {
  const int r = blockIdx.x, dir = blockIdx.y;
  const float* W = dir ? WihB : WihF;
  __shared__ float red[256];
  const int n = threadIdx.x;
  float spb = 0.f;
  if (n < 144) {
    float sws = 0.f, swc = 0.f;
    #pragma unroll
    for (int c = 0; c < 16; ++c) {
      float w = W[(size_t)r * HN_ + c * 144 + n];
      sws += w * ws[c];
      swc += w * wc[c];
      spb += w * (bs[c] + bc[c]);
    }
    const int rm = r % 2304;
    const int g = r / 2304;
    const int nt = rm >> 2, col = (rm & 3) * 4 + g;
    unsigned short* outp = Wpk + (size_t)dir * 2654208;
    int k = n;
    outp[((size_t)(nt * 9 + (k >> 5)) * 64 + ((k >> 3) & 3) * 16 + col) * 8 + (k & 7)] = f2bf(sws);
    k = 144 + n;
    outp[((size_t)(nt * 9 + (k >> 5)) * 64 + ((k >> 3) & 3) * 16 + col) * 8 + (k & 7)] = f2bf(swc);
  }
  red[n] = spb; __syncthreads();
  for (int s = 128; s > 0; s >>= 1) { if (n < s) red[n] += red[n + s]; __syncthreads(); }
  if (n == 0) {
    const float* bih = dir ? bihB : bihF;
    const float* bhh = dir ? bhhB : bhhF;
    beff[dir * G4_ + r] = red[0] + bih[r] + bhh[r];
  }
}

// ---------------- build A fragments for layer-0 input GEMM (bf16) ----------------
__global__ void build_acat_frag(const float* __restrict__ inF, const float* __restrict__ mF,
                                const float* __restrict__ inB, const float* __restrict__ mB,
                                unsigned short* __restrict__ out) {
  int idx = blockIdx.x * 256 + threadIdx.x;   // 18432 frags total
  int lane = idx & 63;
  int ks = (idx >> 6) % 9;
  int mt = (idx / (64 * 9)) % 16;
  int dir = idx / (64 * 9 * 16);
  int m = mt * 16 + (lane & 15);
  int k = ks * 32 + (lane >> 4) * 8;
  int t = m >> 3, b = m & 7;
  const float* src; int kk = k;
  if (k < 144) src = dir ? inB : inF;
  else { src = dir ? mB : mF; kk = k - 144; }
  const float* p = src + ((size_t)b * 32 + t) * 144 + kk;
  v8s o;
  #pragma unroll
  for (int e = 0; e < 8; ++e) o[e] = (short)f2bf(p[e]);
  ((v8s*)out)[idx] = o;
}

// ---------------- pack a [9216 x 2304] weight matrix into gate-interleaved bf16 frags ----------------
__global__ void pack_whh(const float* __restrict__ W, unsigned short* __restrict__ out) {
  int idx = blockIdx.x * 256 + threadIdx.x;   // 576*72*64 = 2,654,208
  int lane = idx & 63;
  int ks = (idx >> 6) % 72;
  int nt = idx / (64 * 72);
  int col = lane & 15, q = lane >> 4;
  int r = (col & 3) * 2304 + nt * 4 + (col >> 2);
  int k = ks * 32 + q * 8;
  const float* src = W + (size_t)r * 2304 + k;
  float4 v0 = *(const float4*)src;
  float4 v1 = *(const float4*)(src + 4);
  v8s o;
  o[0] = (short)f2bf(v0.x); o[1] = (short)f2bf(v0.y);
  o[2] = (short)f2bf(v0.z); o[3] = (short)f2bf(v0.w);
  o[4] = (short)f2bf(v1.x); o[5] = (short)f2bf(v1.y);
  o[6] = (short)f2bf(v1.z); o[7] = (short)f2bf(v1.w);
  ((v8s*)out)[idx] = o;
}

// ---------------- MFMA GEMM over fragment-packed operands; writes Gx[t][nt][col][b] ----------------
__global__ __launch_bounds__(64)
void gemm_frag(const unsigned short* __restrict__ Apk, const unsigned short* __restrict__ Wpk,
               const float* __restrict__ b1, const float* __restrict__ b2,
               float* __restrict__ Gx, int nks) {
  const int lane = threadIdx.x;
  const int nt = blockIdx.x;
  const int mtb = blockIdx.y * 4;
  v4f acc[4] = {};
  const v8s* Bp = (const v8s*)Wpk + (size_t)nt * nks * 64;
  const v8s* Ap = (const v8s*)Apk;
  for (int ks = 0; ks < nks; ++ks) {
    v8s bf = Bp[ks * 64 + lane];
    #pragma unroll
    for (int mi = 0; mi < 4; ++mi) {
      v8s af = Ap[(size_t)((mtb + mi) * nks + ks) * 64 + lane];
      acc[mi] = __builtin_amdgcn_mfma_f32_16x16x32_bf16(af, bf, acc[mi], 0, 0, 0);
    }
  }
  const int col = lane & 15;
  const int jj = col >> 2, g = col & 3;
  const int rw = g * 2304 + nt * 4 + jj;
  float bsum = b1[rw] + (b2 ? b2[rw] : 0.f);
  #pragma unroll
  for (int mi = 0; mi < 4; ++mi)
    #pragma unroll
    for (int r = 0; r < 4; ++r) {
      int m = (mtb + mi) * 16 + (lane >> 4) * 4 + r;
      int t = m >> 3, b = m & 7;
      Gx[((size_t)t * 576 + nt) * 128 + col * 8 + b] = acc[mi][r] + bsum;
    }
}

// ---------------- one LSTM timestep, 4-way split-K MFMA ----------------
// grid (576, ndir), block 256 (4 waves). Block = one nt column; wave w covers ks in [w*18, w*18+18).
// h kept COMPACT (8 batch rows): per dir per parity 18432 u16 (36864 B), read direct from global (L2-hit).
// Wave 0 prefetches Gx (float4 x4) and c into registers BEFORE the MFMA loop (tail latency hidden).
__global__ __launch_bounds__(256, 5)
void lstm_step(const unsigned short* __restrict__ Wpk0, const unsigned short* __restrict__ Wpk1,
               const float* __restrict__ Gx0, const float* __restrict__ Gx1,
               const unsigned short* __restrict__ hin0, const unsigned short* __restrict__ hin1,
               unsigned short* __restrict__ hout0, unsigned short* __restrict__ hout1,
               float* __restrict__ c0, float* __restrict__ c1,
               float* __restrict__ hs0, float* __restrict__ hs1,
               int t, int T) {
  const int dir = blockIdx.y;
  const unsigned short* __restrict__ Wpk = dir ? Wpk1 : Wpk0;
  const float* __restrict__ Gxb = dir ? Gx1 : Gx0;
  const unsigned short* __restrict__ hin = dir ? hin1 : hin0;
  unsigned short* __restrict__ hout = dir ? hout1 : hout0;
  float* __restrict__ cb = dir ? c1 : c0;
  float* __restrict__ hsout = dir ? hs1 : hs0;

  const int lane = threadIdx.x & 63;
  const int wave = threadIdx.x >> 6;
  const int nt = blockIdx.x;

  const int col = lane & 15;
  const int brow = (lane >> 4) * 4;
  const bool act = (wave == 0) && ((lane & 3) == 0) && (lane < 32);

  // early prefetch of gate-phase operands (hidden under the GEMM)
  float4 gxI = {0,0,0,0}, gxF = {0,0,0,0}, gxG = {0,0,0,0}, gxO = {0,0,0,0};
  float cpre[4] = {0.f, 0.f, 0.f, 0.f};
  int jpre = 0;
  if (act) {
    jpre = nt * 4 + (col >> 2);
    const float* Gx = Gxb + (size_t)t * 73728 + (size_t)(nt * 16 + col) * 8 + brow;
    gxI = *(const float4*)(Gx);
    gxF = *(const float4*)(Gx + 8);
    gxG = *(const float4*)(Gx + 16);
    gxO = *(const float4*)(Gx + 24);
    #pragma unroll
    for (int r = 0; r < 4; ++r) cpre[r] = cb[(brow + r) * HN_ + jpre];
  }

  const int afoff = (lane >> 4) * 8 + (lane & 7);   // v8s index within one ks block of 32
  const v8s* __restrict__ Aq = (const v8s*)hin + (size_t)(wave * 18) * 32 + afoff;
  const v8s* __restrict__ Bq = (const v8s*)Wpk + (size_t)nt * 72 * 64 + (size_t)(wave * 18) * 64 + lane;

  v4f acc = {0.f, 0.f, 0.f, 0.f};
  #pragma unroll
  for (int k = 0; k < 18; ++k) {
    v8s af = Aq[k * 32];
    v8s bf = Bq[k * 64];
    acc = __builtin_amdgcn_mfma_f32_16x16x32_bf16(af, bf, acc, 0, 0, 0);
  }

  __shared__ v4f red[3][64];
  if (wave) red[wave - 1][lane] = acc;
  __syncthreads();
  if (wave == 0) {
    acc += red[0][lane];
    acc += red[1][lane];
    acc += red[2][lane];

    // gate gather: cols col^1/col^2/col^3 hold f/g/o gates
    float vI[4], vF[4], vG[4], vO[4];
    #pragma unroll
    for (int r = 0; r < 4; ++r) {
      float a = acc[r];
      vI[r] = a;
      vF[r] = __shfl_xor(a, 1, 64);
      vG[r] = __shfl_xor(a, 2, 64);
      vO[r] = __shfl_xor(a, 3, 64);
    }
    if (act) {
      const float gxi[4] = {gxI.x, gxI.y, gxI.z, gxI.w};
      const float gxf[4] = {gxF.x, gxF.y, gxF.z, gxF.w};
      const float gxg[4] = {gxG.x, gxG.y, gxG.z, gxG.w};
      const float gxo[4] = {gxO.x, gxO.y, gxO.z, gxO.w};
      #pragma unroll
      for (int r = 0; r < 4; ++r) {
        const int b = brow + r;
        const float gi = vI[r] + gxi[r];
        const float gf = vF[r] + gxf[r];
        const float gg = vG[r] + gxg[r];
        const float go = vO[r] + gxo[r];
        const float si = 1.f / (1.f + expf(-gi));
        const float sf = 1.f / (1.f + expf(-gf));
        const float so = 1.f / (1.f + expf(-go));
        const float cn = sf * cpre[r] + si * tanhf(gg);
        cb[b * HN_ + jpre] = cn;
        const float hv = so * tanhf(cn);
        hsout[(size_t)(b * HN_ + jpre) * T + t] = hv;
        hout[((jpre >> 5) * 32 + ((jpre >> 3) & 3) * 8 + b) * 8 + (jpre & 7)] = f2bf(hv);
      }
    }
  }
}

// ---------------- fused combine(tanh) + 2x graph diffusion ----------------
// grid (128 = b*c, t_l/8), block 256. Keeps the [144][8] t-slab in LDS through both hops.
__global__ __launch_bounds__(256)
void gc_fused(const float* __restrict__ hsF, const float* __restrict__ hsB,
              const float* __restrict__ A,
              float* __restrict__ gin, float* __restrict__ x1b, float* __restrict__ x2b,
              int t_l) {
  const int bc = blockIdx.x;
  const int t0 = blockIdx.y * 8;
  __shared__ float g[144][8];
  __shared__ float s1[144][8];
  const size_t base = (size_t)bc * 144 * t_l;
  // phase 1: combine + tanh
  for (int i = threadIdx.x; i < 1152; i += 256) {
    int v = i >> 3, tt = i & 7;
    size_t idx = base + (size_t)v * t_l + t0 + tt;
    float val;
    if (hsB) val = 0.5f * (hsF[idx] + hsB[base + (size_t)v * t_l + (t_l - 1 - (t0 + tt))]);
    else val = hsF[idx];
    val = tanhf(val);
    g[v][tt] = val;
    gin[idx] = val;
  }
  __syncthreads();
  // phase 2: x1 = g @ A
  for (int i = threadIdx.x; i < 1152; i += 256) {
    int w = i >> 3, tt = i & 7;
    float acc = 0.f;
    for (int v = 0; v < 144; ++v) acc += g[v][tt] * A[v * 144 + w];
    s1[w][tt] = acc;
    x1b[base + (size_t)w * t_l + t0 + tt] = acc;
  }
  __syncthreads();
  // phase 3: x2 = x1 @ A
  for (int i = threadIdx.x; i < 1152; i += 256) {
    int w = i >> 3, tt = i & 7;
    float acc = 0.f;
    for (int v = 0; v < 144; ++v) acc += s1[v][tt] * A[v * 144 + w];
    x2b[base + (size_t)w * t_l + t0 + tt] = acc;
  }
}

// ---------------- 1x1 conv over concat(x,x1,x2) + residual accumulate ----------------
__global__ void gc_out(const float* __restrict__ g0, const float* __restrict__ g1,
                       const float* __restrict__ g2, const float* __restrict__ Wg,
                       const float* __restrict__ bg, const float* __restrict__ prev,
                       float* __restrict__ out, int t_l, int total) {
  int idx = blockIdx.x * 256 + threadIdx.x;
  if (idx >= total) return;
  int t = idx % t_l;
  int n = (idx / t_l) % 144;
  int o = (idx / (t_l * 144)) % 16;
  int b = idx / (t_l * 144 * 16);
  float acc = bg[o];
  size_t base = ((size_t)b * 16 * 144 + n) * t_l + t;
  #pragma unroll
  for (int c = 0; c < 16; ++c) {
    size_t s = base + (size_t)c * 144 * t_l;
    acc += Wg[o * 48 + c] * g0[s] + Wg[o * 48 + 16 + c] * g1[s] + Wg[o * 48 + 32 + c] * g2[s];
  }
  if (prev) acc += prev[((size_t)(b * 16 + o) * 144 + n) * 32 + 16 + t];
  out[idx] = acc;
}

// ---------------- batchnorm over go[...,::2]; writes bf16 A-fragments for layer-1 GEMM ----------------
__global__ __launch_bounds__(256)
void bn_xt(const float* __restrict__ go, const float* __restrict__ gamma,
           const float* __restrict__ beta, unsigned short* __restrict__ xbf) {
  int c = blockIdx.x;    // channel
  __shared__ float s1[256], s2[256];
  float sum = 0.f, sq = 0.f;
  for (int i = threadIdx.x; i < 18432; i += 256) {
    int b = i / 2304; int rem = i - b * 2304; int n = rem / 16; int tt = rem & 15;
    float v = go[((size_t)(b * 16 + c) * 144 + n) * 32 + 2 * tt];
    sum += v; sq += v * v;
  }
  s1[threadIdx.x] = sum; s2[threadIdx.x] = sq; __syncthreads();
  for (int s = 128; s > 0; s >>= 1) {
    if (threadIdx.x < s) { s1[threadIdx.x] += s1[threadIdx.x + s]; s2[threadIdx.x] += s2[threadIdx.x + s]; }
    __syncthreads();
  }
  float mean = s1[0] / 18432.f;
  float var = s2[0] / 18432.f - mean * mean;
  float rs = rsqrtf(var + 1e-5f);
  float scale = gamma[c] * rs, shift = beta[c] - mean * scale;
  for (int i = threadIdx.x; i < 18432; i += 256) {
    int b = i / 2304; int rem = i - b * 2304; int n = rem / 16; int tt = rem & 15;
    float v = go[((size_t)(b * 16 + c) * 144 + n) * 32 + 2 * tt];
    int m = tt * 8 + b;
    int k = c * 144 + n;
    size_t pos = ((size_t)((m >> 4) * 72 + (k >> 5)) * 64 + ((k >> 3) & 3) * 16 + (m & 15)) * 8 + (k & 7);
    xbf[pos] = f2bf(v * scale + shift);
  }
}

// ---------------- collapsed epilogue: z = sum_t out1 * Wlo, then out3 = W2(W1 z + b1 S) + ... ----------------
__global__ void ez_kernel(const float* __restrict__ out1, const float* __restrict__ Wlo,
                          float* __restrict__ z) {
  int idx = blockIdx.x * 256 + threadIdx.x;   // 18432 = (b*16+c)*144+n
  const float* p = out1 + (size_t)idx * 16;
  float acc = 0.f;
  #pragma unroll
  for (int tt = 0; tt < 16; ++tt) acc += p[tt] * Wlo[tt];
  z[idx] = acc;
}
__global__ void ef_kernel(const float* __restrict__ z, const float* __restrict__ W1,
                          const float* __restrict__ b1, const float* __restrict__ W2,
                          const float* __restrict__ b2, const float* __restrict__ Wlo,
                          const float* __restrict__ blo, float* __restrict__ out3) {
  int idx = blockIdx.x * 256 + threadIdx.x;   // 36864: (b*32+o2)*144+n
  int n = idx % 144;
  int o2 = (idx / 144) & 31;
  int b = idx / (144 * 32);
  float S = 0.f;
  #pragma unroll
  for (int tt = 0; tt < 16; ++tt) S += Wlo[tt];
  float zr[16];
  const float* zb = z + (size_t)b * 16 * 144 + n;
  #pragma unroll
  for (int c = 0; c < 16; ++c) zr[c] = zb[(size_t)c * 144];
  float acc = blo[0] + b2[o2] * S;
  #pragma unroll
  for (int o = 0; o < 16; ++o) {
    float u = b1[o] * S;
    #pragma unroll
    for (int c = 0; c < 16; ++c) u += W1[o * 16 + c] * zr[c];
    acc += W2[o2 * 16 + o] * u;
  }
  out3[idx] = acc;
}

// ---------------- final MLP ----------------
__global__ void f1_kernel(const float* __restrict__ o3, const float* __restrict__ y,
                          const float* __restrict__ ym, const float* __restrict__ W,
                          const float* __restrict__ bias, float* __restrict__ out) {
  int idx = blockIdx.x * 256 + threadIdx.x;   // 32768
  int k = idx & 127;
  int t = (idx >> 7) & 31;
  int b = idx >> 12;
  float acc = bias[k];
  size_t rb = (size_t)(b * 32 + t) * 144;
  const float* wr = W + k * 432;
  for (int n = 0; n < 144; ++n)
    acc += o3[rb + n] * wr[n] + y[rb + n] * wr[144 + n] + ym[rb + n] * wr[288 + n];
  out[idx] = acc;
}
__global__ void f2_kernel(const float* __restrict__ f1b, const float* __restrict__ W,
                          const float* __restrict__ bias, float* __restrict__ out) {
  int idx = blockIdx.x * 256 + threadIdx.x;   // 36864
  int n = idx % 144;
  int t = (idx / 144) % 32;
  int b = idx / (144 * 32);
  float acc = bias[n];
  size_t fb = (size_t)(b * 32 + t) * 128;
  const float* wr = W + n * 128;
  #pragma unroll 4
  for (int k = 0; k < 128; ++k) acc += f1b[fb + k] * wr[k];
  out[idx] = acc;
}

extern "C" void kernel_launch(void* const* d_in, const int* in_sizes, int n_in,
                              void* d_out, int out_size, void* d_ws, size_t ws_size,
                              hipStream_t stream) {
  const float* input_tensor = (const float*)d_in[0];
  const float* mask_    = (const float*)d_in[1];
  const float* input_bw = (const float*)d_in[2];
  const float* mask_bw  = (const float*)d_in[3];
  const float* y_in     = (const float*)d_in[4];
  const float* ymask    = (const float*)d_in[5];
  const float* ws_p = (const float*)d_in[6];
  const float* bs_p = (const float*)d_in[7];
  const float* wc_p = (const float*)d_in[8];
  const float* bc_p = (const float*)d_in[9];
  const float* nv1 = (const float*)d_in[10];
  const float* nv2 = (const float*)d_in[11];
  const float* Wih_fw = (const float*)d_in[12];
  const float* Whh_fw = (const float*)d_in[13];
  const float* bih_fw = (const float*)d_in[14];
  const float* bhh_fw = (const float*)d_in[15];
  const float* Wih_bw = (const float*)d_in[16];
  const float* Whh_bw = (const float*)d_in[17];
  const float* bih_bw = (const float*)d_in[18];
  const float* bhh_bw = (const float*)d_in[19];
  const float* Wg   = (const float*)d_in[20];
  const float* bg   = (const float*)d_in[21];
  const float* gam  = (const float*)d_in[22];
  const float* bet  = (const float*)d_in[23];
  const float* W_end1 = (const float*)d_in[24];
  const float* b_end1 = (const float*)d_in[25];
  const float* W_end2 = (const float*)d_in[26];
  const float* b_end2 = (const float*)d_in[27];
  const float* W_lo = (const float*)d_in[28];
  const float* b_lo = (const float*)d_in[29];
  const float* W_f1 = (const float*)d_in[30];
  const float* b_f1 = (const float*)d_in[31];
  const float* W_f2 = (const float*)d_in[32];
  const float* b_f2 = (const float*)d_in[33];

  char* base = (char*)d_ws;
  size_t off = 0;
  auto alloc = [&](size_t bytes) -> char* {
    char* p = base + off;
    off += (bytes + 255) & ~(size_t)255;
    return p;
  };
  float* adp   = (float*)alloc(144 * 144 * 4);
  unsigned short* Weffpk = (unsigned short*)alloc((size_t)2 * 2654208 * 2);  // 10.6 MB
  float* beff  = (float*)alloc(2 * G4_ * 4);
  unsigned short* acatf  = (unsigned short*)alloc((size_t)2 * 73728 * 2);
  float* GxF   = (float*)alloc((size_t)32 * 73728 * 4);   // 9.44 MB
  float* GxB   = (float*)alloc((size_t)32 * 73728 * 4);
  char*  hz    = alloc(442368);                            // compact h dbl-bufs + c bufs (zeroed)
  float* hsF   = (float*)alloc((size_t)589824 * 4);
  float* hsB   = (float*)alloc((size_t)589824 * 4);
  float* hsL   = (float*)alloc((size_t)294912 * 4);
  float* gin   = (float*)alloc((size_t)589824 * 4);
  float* x1b   = (float*)alloc((size_t)589824 * 4);
  float* x2b   = (float*)alloc((size_t)589824 * 4);
  float* out0  = (float*)alloc((size_t)589824 * 4);
  float* out1  = (float*)alloc((size_t)294912 * 4);
  unsigned short* xbf = (unsigned short*)alloc((size_t)294912 * 2);
  float* zbuf  = (float*)alloc((size_t)18432 * 4);
  float* out3  = (float*)alloc((size_t)36864 * 4);
  float* f1b   = (float*)alloc((size_t)32768 * 4);
  unsigned short* P0 = (unsigned short*)alloc((size_t)2654208 * 8 * 2);  // 42.5 MB
  unsigned short* P1 = (unsigned short*)alloc((size_t)2654208 * 8 * 2);

  unsigned short* hF[2] = {(unsigned short*)hz,            (unsigned short*)(hz + 36864)};
  unsigned short* hB[2] = {(unsigned short*)(hz + 73728),  (unsigned short*)(hz + 110592)};
  unsigned short* hL[2] = {(unsigned short*)(hz + 147456), (unsigned short*)(hz + 184320)};
  float* cF = (float*)(hz + 221184);
  float* cB = (float*)(hz + 294912);
  float* cL = (float*)(hz + 368640);

  hipMemsetAsync(hz, 0, 442368, stream);

  adp_kernel<<<144, 256, 0, stream>>>(nv1, nv2, adp);
  eff_weights<<<dim3(G4_, 2), 256, 0, stream>>>(Wih_fw, Wih_bw, bih_fw, bhh_fw, bih_bw, bhh_bw,
                                                ws_p, bs_p, wc_p, bc_p, Weffpk, beff);
  build_acat_frag<<<72, 256, 0, stream>>>(input_tensor, mask_, input_bw, mask_bw, acatf);
  gemm_frag<<<dim3(576, 4), 64, 0, stream>>>(acatf, Weffpk, beff, nullptr, GxF, 9);
  gemm_frag<<<dim3(576, 4), 64, 0, stream>>>(acatf + 73728, Weffpk + 2654208, beff + G4_, nullptr, GxB, 9);
  pack_whh<<<10368, 256, 0, stream>>>(Whh_fw, P0);
  pack_whh<<<10368, 256, 0, stream>>>(Whh_bw, P1);

  // ---- layer-0 scan (fw + bw concurrently), 4-way split-K per step ----
  for (int t = 0; t < 32; ++t) {
    lstm_step<<<dim3(576, 2), 256, 0, stream>>>(
        P0, P1, GxF, GxB,
        hF[t & 1], hB[t & 1], hF[(t + 1) & 1], hB[(t + 1) & 1],
        cF, cB, hsF, hsB, t, 32);
  }

  gc_fused<<<dim3(128, 4), 256, 0, stream>>>(hsF, hsB, adp, gin, x1b, x2b, 32);
  gc_out<<<2304, 256, 0, stream>>>(gin, x1b, x2b, Wg, bg, nullptr, out0, 32, 589824);
  bn_xt<<<16, 256, 0, stream>>>(out0, gam, bet, xbf);

  const size_t WL1_off = (size_t)G4_ * HN_;
  pack_whh<<<10368, 256, 0, stream>>>(Wih_fw + WL1_off, P1);   // layer-1 input weights
  gemm_frag<<<dim3(576, 2), 64, 0, stream>>>(xbf, P1, bih_fw + G4_, bhh_fw + G4_, GxF, 72);
  pack_whh<<<10368, 256, 0, stream>>>(Whh_fw + WL1_off, P0);   // layer-1 recurrent weights

  // ---- layer-1 scan ----
  for (int t = 0; t < 16; ++t) {
    lstm_step<<<dim3(576, 1), 256, 0, stream>>>(
        P0, P0, GxF, GxF,
        hL[t & 1], hL[t & 1], hL[(t + 1) & 1], hL[(t + 1) & 1],
        cL, cL, hsL, hsL, t, 16);
  }

  gc_fused<<<dim3(128, 2), 256, 0, stream>>>(hsL, nullptr, adp, gin, x1b, x2b, 16);
  gc_out<<<1152, 256, 0, stream>>>(gin, x1b, x2b, Wg + 16 * 48, bg + 16, out0, out1, 16, 294912);

  ez_kernel<<<72, 256, 0, stream>>>(out1, W_lo, zbuf);
  ef_kernel<<<144, 256, 0, stream>>>(zbuf, W_end1, b_end1, W_end2, b_end2, W_lo, b_lo, out3);
  f1_kernel<<<128, 256, 0, stream>>>(out3, y_in, ymask, W_f1, b_f1, f1b);
  f2_kernel<<<144, 256, 0, stream>>>(f1b, W_f2, b_f2, (float*)d_out);
}